// Round 1
// baseline (142.757 us; speedup 1.0000x reference)
//
#include <hip/hip_runtime.h>
#include <math.h>

constexpr int kH = 64, kW = 128, kB = 2, kS = 4;
constexpr int kNP = kH * kW;          // 8192 points per set
constexpr int kPairs = kB * kS;       // 8
constexpr int kDirs = kPairs * 2;     // 16
constexpr float kPen = 32768.0f;      // exclusion penalty (bf16-exact pow2)
constexpr float kBias = 0.25f;        // per-side positivity bias; matrix carries 0.5
constexpr float kPi = 3.14159265358979323846f;
constexpr float kFovUp = 3.0f * kPi / 180.0f;
constexpr float kFovDown = -25.0f * kPi / 180.0f;

typedef short short8 __attribute__((ext_vector_type(8)));
typedef unsigned short ushort8 __attribute__((ext_vector_type(8)));
typedef float floatx4 __attribute__((ext_vector_type(4)));

// R12: pair-shared matrix. Dirs d and d^1 share the same 8192x8192 distance
// matrix; we now put BOTH sides' norm+penalty constants into the MFMA K-slots
// so one pass yields row-mins (dir d0) AND column-mins (dir d1). Grid halves
// (1024 blocks = 4/CU), MFMA count halves.
constexpr int NCC = 8;                // candidate chunks
constexpr int CCH = kNP / NCC;        // 1024 candidates
constexpr int NQB = 16;               // query blocks (8192/512)
constexpr int BPP = NQB * NCC;        // 128 blocks per pair

// ws layout (float offsets)
// pts  : [kDirs][kNP] float4 -> 524288 floats @ 0   (2 MB)
// min  : [kDirs][kNP] u32    -> 131072 @ 524288     (0.5 MB)
// mval : [kDirs] f32         -> 16 @ 655360
// dcnt : [kDirs] u32         -> 16 @ 655376 (only first kPairs used now)
// acnt : u32                 -> 1  @ 655392
constexpr size_t OFF_MIN = 524288;
constexpr size_t OFF_MVAL = 655360;
constexpr size_t OFF_DCNT = 655376;
constexpr size_t OFF_ACNT = 655392;

__device__ __forceinline__ unsigned short f2bf(float v) {
  unsigned u = __float_as_uint(v);
  unsigned r = u + 0x7FFFu + ((u >> 16) & 1u);   // RNE
  return (unsigned short)(r >> 16);
}
__device__ __forceinline__ float bf2f(unsigned short b) {
  return __uint_as_float(((unsigned)b) << 16);
}

// Candidate record F (16 bf16 K-slots) paired with query record G:
//  k : 0    1    2    3    4    5    6    7  | 8    9    10   11   12   13   14   15
//  F : Xh   Xl   Xh   Yh   Yl   Yh   Zh   Zl | Zh   Ch   Cl   Cl2  1    1    1    0
//  G : xh   xh   xl   yh   yh   yl   zh   zh | zl   1    1    1    Wh   Wl   Wl2  0
// sum_k F*G = -2 q.c + ct + cq = dist^2 + pen_c + pen_q + 0.5  (drops lo*lo only)
// All matrix values are therefore > 0 -> raw float bits are uint-min-orderable
// (no sign-flip encode needed on any atomicMin path).

__global__ __launch_bounds__(256) void prep_kernel(
    const float* __restrict__ rv, const float* __restrict__ tgt,
    float4* __restrict__ pts, unsigned* __restrict__ minarr,
    float* __restrict__ mval, unsigned* __restrict__ dcnt,
    unsigned* __restrict__ acnt) {
  int idx = blockIdx.x * 256 + threadIdx.x;   // [0, kPairs*kNP)
  int p = idx >> 13;
  int k = idx & (kNP - 1);
  int h = k >> 7;
  int w = k & 127;

  float r = rv[idx];
  float pitch = (1.0f - (h + 0.5f) * (1.0f / kH)) * (kFovUp - kFovDown) + kFovDown;
  float yaw = -(((w + 0.5f) * (1.0f / kW)) * 2.0f - 1.0f) * kPi;
  float cp = __cosf(pitch), sp = __sinf(pitch);
  float cy = __cosf(yaw), sy = __sinf(yaw);
  float px = r * cp * cy, py = r * cp * sy, pz = r * sp;
  float mo = (r > 0.0f) ? 1.0f : 0.0f;

  const float* tb = tgt + (size_t)p * 4 * kNP;
  float mt = (tb[k] > 0.0f) ? 1.0f : 0.0f;
  float tx = tb[kNP + k], ty = tb[2 * kNP + k], tz = tb[3 * kNP + k];

  float no = px * px + py * py + pz * pz;
  float nt = tx * tx + ty * ty + tz * tz;
  float co = no + kPen * (1.0f - mo) + kBias;
  float ct = nt + kPen * (1.0f - mt) + kBias;

  int d0 = 2 * p, d1 = d0 + 1;
  // pts.w < 16384 <=> valid point; equals |p|^2 + kBias then.
  pts[(size_t)d0 * kNP + k] = make_float4(px, py, pz, co);
  pts[(size_t)d1 * kNP + k] = make_float4(tx, ty, tz, ct);

  minarr[(size_t)d0 * kNP + k] = 0xFFFFFFFFu;
  minarr[(size_t)d1 * kNP + k] = 0xFFFFFFFFu;
  if (idx < kDirs) { dcnt[idx] = 0u; mval[idx] = 0.0f; }
  if (idx == kDirs) *acnt = 0u;
}

__global__ __launch_bounds__(256, 4) void nn_kernel(
    const float4* __restrict__ pts, unsigned* __restrict__ minarr,
    float* __restrict__ mval, unsigned* __restrict__ dcnt,
    unsigned* __restrict__ acnt, float* __restrict__ out) {
  // 32 KB candidate records (64 tiles of [16 x lo8][16 x hi8]) + 32 B zero tile
  __shared__ __align__(16) unsigned short sc[CCH * 16 + 16];
  __shared__ unsigned cminLds[CCH];   // per-block candidate mins (raw float bits)
  __shared__ unsigned s_ticket;
  __shared__ float sred[16];

  int bid = blockIdx.x;
  int dp = bid >> 7;            // pair index, 128 blocks per pair
  int d0 = 2 * dp, d1 = d0 + 1; // d0 = query side (rv), d1 = candidate side (tgt)
  int qb = (bid >> 3) & 15;
  int ch = bid & 7;
  int t = threadIdx.x;

  // ---- build candidate records in LDS from pts[d1] ----
  const float4* cand = pts + (size_t)d1 * kNP + ch * CCH;
  const unsigned short one_bfu = 0x3F80;  // bf16(1.0)
#pragma unroll
  for (int i = 0; i < 4; ++i) {
    int j = t + i * 256;
    float4 P = cand[j];
    float X = -2.0f * P.x, Y = -2.0f * P.y, Z = -2.0f * P.z;
    float ct = P.w;
    unsigned short Xh = f2bf(X), Yh = f2bf(Y), Zh = f2bf(Z);
    unsigned short Xl = f2bf(X - bf2f(Xh));
    unsigned short Yl = f2bf(Y - bf2f(Yh));
    unsigned short Zl = f2bf(Z - bf2f(Zh));
    unsigned short Ch = f2bf(ct);
    float c1 = ct - bf2f(Ch);
    unsigned short Cl = f2bf(c1);
    unsigned short Cl2 = f2bf(c1 - bf2f(Cl));
    unsigned short* dst = sc + (j >> 4) * 256 + (j & 15) * 8;
    *(ushort8*)dst = (ushort8){Xh, Xl, Xh, Yh, Yl, Yh, Zh, Zl};
    *(ushort8*)(dst + 128) =
        (ushort8){Zh, Ch, Cl, Cl2, one_bfu, one_bfu, one_bfu, 0};
  }
#pragma unroll
  for (int i = 0; i < 4; ++i) cminLds[t + i * 256] = 0xFFFFFFFFu;
  if (t < 2) ((float4*)(sc + CCH * 16))[t] = make_float4(0.f, 0.f, 0.f, 0.f);
  __syncthreads();

  int wave = t >> 6, lane = t & 63;
  int n = lane & 15, q = lane >> 4;    // q = K-quad for inputs / row-quad for output
  int qbase = d0 * kNP + qb * 512 + wave * 128;

  const short one_bf = (short)0x3F80;
  short8 bfr[8];
  float mn[8];
#pragma unroll
  for (int i = 0; i < 8; ++i) {
    short8 b = (short8){0, 0, 0, 0, 0, 0, 0, 0};
    if (q < 2) {
      float4 P = pts[qbase + i * 16 + n];
      unsigned short xh = f2bf(P.x), yh = f2bf(P.y), zh = f2bf(P.z);
      unsigned short xl = f2bf(P.x - bf2f(xh));
      unsigned short yl = f2bf(P.y - bf2f(yh));
      unsigned short zl = f2bf(P.z - bf2f(zh));
      if (q == 0) {
        b = (short8){(short)xh, (short)xh, (short)xl, (short)yh,
                     (short)yh, (short)yl, (short)zh, (short)zh};
      } else {
        unsigned short Wh = f2bf(P.w);
        float w1 = P.w - bf2f(Wh);
        unsigned short Wl = f2bf(w1);
        unsigned short Wl2 = f2bf(w1 - bf2f(Wl));
        b = (short8){(short)zl, one_bf, one_bf, one_bf,
                     (short)Wh, (short)Wl, (short)Wl2, 0};
      }
    }
    bfr[i] = b;
    mn[i] = 3.0e38f;
  }

  floatx4 zc = {0.0f, 0.0f, 0.0f, 0.0f};
  // A addressing: quads 0/1 walk their K-slice (stride 512 B); quads 2/3 sit
  // on the shared zero tile (same-address broadcast). No cndmask in the loop.
  const unsigned short* aptr = (q < 2) ? (sc + q * 128 + n * 8) : (sc + CCH * 16);
  int astep = (q < 2) ? 256 : 0;
  int cq4 = (lane >> 4) * 4;          // output rows (candidates) owned by this lane
  bool leader = (n == 0);

#pragma unroll 2
  for (int ctile = 0; ctile < CCH / 16; ++ctile) {
    short8 a = *(const short8*)aptr;
    aptr += astep;
    float c0 = 3.0e38f, c1 = 3.0e38f, c2 = 3.0e38f, c3 = 3.0e38f;
#pragma unroll
    for (int i = 0; i < 8; i += 2) {
      floatx4 dA = __builtin_amdgcn_mfma_f32_16x16x32_bf16(a, bfr[i], zc, 0, 0, 0);
      floatx4 dB = __builtin_amdgcn_mfma_f32_16x16x32_bf16(a, bfr[i + 1], zc, 0, 0, 0);
      // row-min folds (per-query, over candidate rows) — 2 v_min3 each
      float uA = fminf(fminf(dA[0], dA[1]), dA[2]);
      mn[i] = fminf(fminf(uA, dA[3]), mn[i]);
      float uB = fminf(fminf(dB[0], dB[1]), dB[2]);
      mn[i + 1] = fminf(fminf(uB, dB[3]), mn[i + 1]);
      // col-min folds (per-candidate, over the two query tiles) — 4 v_min3
      c0 = fminf(fminf(dA[0], dB[0]), c0);
      c1 = fminf(fminf(dA[1], dB[1]), c1);
      c2 = fminf(fminf(dA[2], dB[2]), c2);
      c3 = fminf(fminf(dA[3], dB[3]), c3);
    }
    // 16-lane butterfly over the query dimension (ds_swizzle = LDS pipe)
#pragma unroll
    for (int s = 1; s <= 8; s <<= 1) {
      c0 = fminf(c0, __shfl_xor(c0, s));
      c1 = fminf(c1, __shfl_xor(c1, s));
      c2 = fminf(c2, __shfl_xor(c2, s));
      c3 = fminf(c3, __shfl_xor(c3, s));
    }
    if (leader) {
      // candidates ctile*16 + cq4 .. +3; banks 2-way at worst (free per m136)
      unsigned* cp = cminLds + ctile * 16 + cq4;
      atomicMin(cp + 0, __float_as_uint(c0));
      atomicMin(cp + 1, __float_as_uint(c1));
      atomicMin(cp + 2, __float_as_uint(c2));
      atomicMin(cp + 3, __float_as_uint(c3));
    }
  }

  // ---- query-side (dir d0) global merge: values positive -> raw-bit ordering
#pragma unroll
  for (int i = 0; i < 8; ++i) {
    float m = mn[i];
    m = fminf(m, __shfl_xor(m, 16));
    m = fminf(m, __shfl_xor(m, 32));
    if (lane < 16)
      atomicMin(&minarr[qbase + i * 16 + lane], __float_as_uint(m));
  }

  // ---- candidate-side (dir d1) global merge ----
  __syncthreads();   // cminLds ds_atomics done block-wide
  {
    unsigned* garr = minarr + (size_t)d1 * kNP + ch * CCH;
#pragma unroll
    for (int i = 0; i < 4; ++i) {
      int c = t + i * 256;
      atomicMin(&garr[c], cminLds[c]);
    }
  }

  // ---- last block of this pair reduces BOTH dirs ----
  // NO __threadfence (R8/R10/R11 post-mortem: device fences emit
  // buffer_wbl2/buffer_inv that serialized device-wide). All cross-block data
  // moves through device-scope atomics; __syncthreads' implicit
  // s_waitcnt vmcnt(0) drains our atomicMins before the ticket increment.
  __syncthreads();
  if (t == 0)
    s_ticket = __hip_atomic_fetch_add(&dcnt[dp], 1u, __ATOMIC_RELAXED,
                                      __HIP_MEMORY_SCOPE_AGENT);
  __syncthreads();
  if (s_ticket != (unsigned)(BPP - 1)) return;

  float ws0 = 0.0f, ms0 = 0.0f, ws1 = 0.0f, ms1 = 0.0f;
#pragma unroll 2
  for (int j = 0; j < 32; ++j) {
    int k = j * 256 + t;
    {
      unsigned u = __hip_atomic_load(&minarr[(size_t)d0 * kNP + k],
                                     __ATOMIC_RELAXED, __HIP_MEMORY_SCOPE_AGENT);
      float4 P = pts[(size_t)d0 * kNP + k];
      if (P.w < 16384.0f) { ws0 += __uint_as_float(u) - 2.0f * kBias; ms0 += 1.0f; }
    }
    {
      unsigned u = __hip_atomic_load(&minarr[(size_t)d1 * kNP + k],
                                     __ATOMIC_RELAXED, __HIP_MEMORY_SCOPE_AGENT);
      float4 P = pts[(size_t)d1 * kNP + k];
      if (P.w < 16384.0f) { ws1 += __uint_as_float(u) - 2.0f * kBias; ms1 += 1.0f; }
    }
  }
#pragma unroll
  for (int off = 32; off; off >>= 1) {
    ws0 += __shfl_down(ws0, off); ms0 += __shfl_down(ms0, off);
    ws1 += __shfl_down(ws1, off); ms1 += __shfl_down(ms1, off);
  }
  if ((t & 63) == 0) {
    int w = t >> 6;
    sred[w] = ws0; sred[4 + w] = ms0; sred[8 + w] = ws1; sred[12 + w] = ms1;
  }
  __syncthreads();
  if (t == 0) {
    float W0 = sred[0] + sred[1] + sred[2] + sred[3];
    float M0 = sred[4] + sred[5] + sred[6] + sred[7];
    float W1 = sred[8] + sred[9] + sred[10] + sred[11];
    float M1 = sred[12] + sred[13] + sred[14] + sred[15];
    __hip_atomic_store(&mval[d0], W0 / fmaxf(M0, 1.0f), __ATOMIC_RELAXED,
                       __HIP_MEMORY_SCOPE_AGENT);
    __hip_atomic_store(&mval[d1], W1 / fmaxf(M1, 1.0f), __ATOMIC_RELAXED,
                       __HIP_MEMORY_SCOPE_AGENT);
    // ACQ_REL: release publishes our mval stores, acquire lets the final
    // winner read the other pairs' mvals. Only kPairs of these per launch.
    s_ticket = __hip_atomic_fetch_add(acnt, 1u, __ATOMIC_ACQ_REL,
                                      __HIP_MEMORY_SCOPE_AGENT);
  }
  __syncthreads();
  if (s_ticket != (unsigned)(kPairs - 1)) return;
  // ---- very last block combines 16 dir values into the 12 outputs ----
  if (t == 0) {
    float mv[kDirs];
    for (int dd = 0; dd < kDirs; ++dd)
      mv[dd] = __hip_atomic_load(&mval[dd], __ATOMIC_RELAXED,
                                 __HIP_MEMORY_SCOPE_AGENT);
    for (int s = 0; s < kS; ++s) {
      float acc = 0.0f;
      for (int b = 0; b < kB; ++b) {
        int p = b * kS + s;
        float tens = mv[2 * p] + mv[2 * p + 1];
        out[kS + s * kB + b] = tens;
        acc += tens;
      }
      out[s] = acc * (1.0f / kB);
    }
  }
}

extern "C" void kernel_launch(void* const* d_in, const int* in_sizes, int n_in,
                              void* d_out, int out_size, void* d_ws, size_t ws_size,
                              hipStream_t stream) {
  const float* rv = (const float*)d_in[0];
  const float* tgt = (const float*)d_in[1];
  float* ws = (float*)d_ws;
  float4* pts = (float4*)ws;
  unsigned* minarr = (unsigned*)(ws + OFF_MIN);
  float* mval = ws + OFF_MVAL;
  unsigned* dcnt = (unsigned*)(ws + OFF_DCNT);
  unsigned* acnt = (unsigned*)(ws + OFF_ACNT);
  float* out = (float*)d_out;

  hipLaunchKernelGGL(prep_kernel, dim3(kPairs * kNP / 256), dim3(256), 0, stream,
                     rv, tgt, pts, minarr, mval, dcnt, acnt);
  hipLaunchKernelGGL(nn_kernel, dim3(kPairs * NQB * NCC), dim3(256), 0, stream,
                     pts, minarr, mval, dcnt, acnt, out);
}

// Round 2
// 99.123 us; speedup vs baseline: 1.4402x; 1.4402x over previous
//
#include <hip/hip_runtime.h>
#include <math.h>

constexpr int kH = 64, kW = 128, kB = 2, kS = 4;
constexpr int kNP = kH * kW;          // 8192 points per set
constexpr int kPairs = kB * kS;       // 8
constexpr int kDirs = kPairs * 2;     // 16
constexpr float kPen = 32768.0f;      // exclusion penalty (bf16-exact pow2)
constexpr float kPi = 3.14159265358979323846f;
constexpr float kFovUp = 3.0f * kPi / 180.0f;
constexpr float kFovDown = -25.0f * kPi / 180.0f;

typedef short short8 __attribute__((ext_vector_type(8)));
typedef unsigned short ushort8 __attribute__((ext_vector_type(8)));
typedef float floatx16 __attribute__((ext_vector_type(16)));

// R13: back to the R11 per-dir register-local structure (R12 post-mortem:
// pair-sharing's per-ctile cross-lane flush stalled the MFMA pipe to 15%),
// but with v_mfma_f32_32x32x16_bf16. Our record needs only 12 K-slots, so
// K=16 (not K=32) suffices -> 2x output entries per MFMA cycle
// (0.033 vs 0.066 cyc/SIMD per entry). MFMA floor: 28.8 -> 14.4 us.
// Row-min is layout-agnostic: min over 16 regs + shfl_xor(32) covers all 32
// candidate rows regardless of the reg->row permutation; only col=lane&31
// (HW-verified, m74/m101) is relied upon for query attribution.
constexpr int NCC = 8;                // candidate chunks
constexpr int CCH = kNP / NCC;        // 1024 candidates per chunk
constexpr int NQB = 8;                // query blocks (8192/1024)
constexpr int BPD = NQB * NCC;        // 64 blocks per dir
constexpr int QT = 8;                 // 32-query tiles per wave (256 q/wave)
// grid = 16 dirs * 8 * 8 = 1024 blocks = exactly 4 per CU (one clean round)

// ws layout (float offsets)
// pts  : [kDirs][kNP] float4 -> 524288 floats @ 0   (2 MB)
// min  : [kDirs][kNP] u32    -> 131072 @ 524288     (0.5 MB)
// mval : [kDirs] f32         -> 16 @ 655360
// dcnt : [kDirs] u32         -> 16 @ 655376
// acnt : u32                 -> 1  @ 655392
constexpr size_t OFF_MIN = 524288;
constexpr size_t OFF_MVAL = 655360;
constexpr size_t OFF_DCNT = 655376;
constexpr size_t OFF_ACNT = 655392;

__device__ __forceinline__ unsigned short f2bf(float v) {
  unsigned u = __float_as_uint(v);
  unsigned r = u + 0x7FFFu + ((u >> 16) & 1u);   // RNE
  return (unsigned short)(r >> 16);
}
__device__ __forceinline__ float bf2f(unsigned short b) {
  return __uint_as_float(((unsigned)b) << 16);
}

// Candidate record F (16 bf16 K-slots, K=16 MFMA) with query record G:
//  k : 0    1    2    3    4    5    6    7  | 8    9    10   11   12-15
//  F : Xh   Xl   Xh   Yh   Yl   Yh   Zh   Zl | Zh   Ch   Cl   Cl2  0
//  G : xh   xh   xl   yh   yh   yl   zh   zh | zl   1    1    1    0
// sum_k F*G = X*x + Y*y + Z*z + ct  (drops only lo*lo terms ~2e-4)

__global__ __launch_bounds__(256) void prep_kernel(
    const float* __restrict__ rv, const float* __restrict__ tgt,
    float4* __restrict__ pts, unsigned* __restrict__ minarr,
    float* __restrict__ mval, unsigned* __restrict__ dcnt,
    unsigned* __restrict__ acnt) {
  int idx = blockIdx.x * 256 + threadIdx.x;   // [0, kPairs*kNP)
  int p = idx >> 13;
  int k = idx & (kNP - 1);
  int h = k >> 7;
  int w = k & 127;

  float r = rv[idx];
  float pitch = (1.0f - (h + 0.5f) * (1.0f / kH)) * (kFovUp - kFovDown) + kFovDown;
  float yaw = -(((w + 0.5f) * (1.0f / kW)) * 2.0f - 1.0f) * kPi;
  float cp = __cosf(pitch), sp = __sinf(pitch);
  float cy = __cosf(yaw), sy = __sinf(yaw);
  float px = r * cp * cy, py = r * cp * sy, pz = r * sp;
  float mo = (r > 0.0f) ? 1.0f : 0.0f;

  const float* tb = tgt + (size_t)p * 4 * kNP;
  float mt = (tb[k] > 0.0f) ? 1.0f : 0.0f;
  float tx = tb[kNP + k], ty = tb[2 * kNP + k], tz = tb[3 * kNP + k];

  float no = px * px + py * py + pz * pz;
  float nt = tx * tx + ty * ty + tz * tz;
  float co = no + kPen * (1.0f - mo);
  float ct = nt + kPen * (1.0f - mt);

  int d0 = 2 * p, d1 = d0 + 1;
  // pts.w < 16384 <=> valid point; equals |p|^2 then. Candidates of dir d
  // are exactly pts[d^1] (dir0 candidates = tgt pts = dir1 queries).
  pts[(size_t)d0 * kNP + k] = make_float4(px, py, pz, co);
  pts[(size_t)d1 * kNP + k] = make_float4(tx, ty, tz, ct);

  minarr[(size_t)d0 * kNP + k] = 0xFFFFFFFFu;
  minarr[(size_t)d1 * kNP + k] = 0xFFFFFFFFu;
  if (idx < kDirs) { dcnt[idx] = 0u; mval[idx] = 0.0f; }
  if (idx == kDirs) *acnt = 0u;
}

__global__ __launch_bounds__(256, 4) void nn_kernel(
    const float4* __restrict__ pts, unsigned* __restrict__ minarr,
    float* __restrict__ mval, unsigned* __restrict__ dcnt,
    unsigned* __restrict__ acnt, float* __restrict__ out) {
  // 32 KB candidate records: 32 ctiles of 1 KB = [32 rows x 8 lo][32 rows x 8 hi]
  // laid out so lane l's A-fragment is at byte offset l*16 (linear ds_read_b128).
  // +1 KB slack so the loop's A-prefetch may harmlessly overread one tile.
  __shared__ __align__(16) unsigned short sc[CCH * 16 + 512];
  __shared__ unsigned s_ticket;
  __shared__ float sw[4], sm[4];

  int bid = blockIdx.x;
  int d = bid >> 6;            // 64 blocks per dir
  int qb = (bid >> 3) & 7;
  int ch = bid & 7;
  int t = threadIdx.x;

  // ---- build candidate records in LDS directly from pts[d^1] ----
  const float4* cand = pts + (size_t)(d ^ 1) * kNP + ch * CCH;
#pragma unroll
  for (int i = 0; i < 4; ++i) {
    int j = t + i * 256;
    float4 P = cand[j];
    float X = -2.0f * P.x, Y = -2.0f * P.y, Z = -2.0f * P.z;
    float ct = P.w;
    unsigned short Xh = f2bf(X), Yh = f2bf(Y), Zh = f2bf(Z);
    unsigned short Xl = f2bf(X - bf2f(Xh));
    unsigned short Yl = f2bf(Y - bf2f(Yh));
    unsigned short Zl = f2bf(Z - bf2f(Zh));
    unsigned short Ch = f2bf(ct);
    float c1 = ct - bf2f(Ch);
    unsigned short Cl = f2bf(c1);
    unsigned short Cl2 = f2bf(c1 - bf2f(Cl));
    // ctile (j>>5): lo-half (k0..7) at slot (j&31), hi-half (k8..15) at +32
    unsigned short* dst = sc + (j >> 5) * 512 + (j & 31) * 8;
    *(ushort8*)dst = (ushort8){Xh, Xl, Xh, Yh, Yl, Yh, Zh, Zl};
    *(ushort8*)(dst + 256) = (ushort8){Zh, Ch, Cl, Cl2, 0, 0, 0, 0};
  }
  __syncthreads();

  int wave = t >> 6, lane = t & 63;
  int col = lane & 31, half = lane >> 5;   // B: col = lane&31 (HW-verified)
  int qbase = d * kNP + qb * 1024 + wave * 256;

  const short one_bf = (short)0x3F80;  // bf16(1.0)
  short8 bq[QT];
  float mn[QT];
#pragma unroll
  for (int qt = 0; qt < QT; ++qt) {
    float4 P = pts[qbase + qt * 32 + col];
    unsigned short xh = f2bf(P.x), yh = f2bf(P.y), zh = f2bf(P.z);
    unsigned short xl = f2bf(P.x - bf2f(xh));
    unsigned short yl = f2bf(P.y - bf2f(yh));
    unsigned short zl = f2bf(P.z - bf2f(zh));
    short8 b;
    if (half == 0)
      b = (short8){(short)xh, (short)xh, (short)xl, (short)yh,
                   (short)yh, (short)yl, (short)zh, (short)zh};
    else
      b = (short8){(short)zl, one_bf, one_bf, one_bf, 0, 0, 0, 0};
    bq[qt] = b;
    mn[qt] = 3.0e38f;
  }

  floatx16 zc = {0.0f, 0.0f, 0.0f, 0.0f, 0.0f, 0.0f, 0.0f, 0.0f,
                 0.0f, 0.0f, 0.0f, 0.0f, 0.0f, 0.0f, 0.0f, 0.0f};

  // A fragment: lane l holds row l&31, K-half l>>5 -> linear offset l*16 B.
  const short8* ap = (const short8*)sc + lane;   // stride 64 short8s per ctile
  short8 a = ap[0];
#pragma unroll 2
  for (int ctile = 0; ctile < CCH / 32; ++ctile) {
    short8 an = ap[(ctile + 1) * 64];   // prefetch next tile (slack covers last)
#pragma unroll
    for (int qt = 0; qt < QT; ++qt) {
      floatx16 dr =
          __builtin_amdgcn_mfma_f32_32x32x16_bf16(a, bq[qt], zc, 0, 0, 0);
      // 16->1 row-min fold, min3-shaped (compiler emits ~8 v_min3)
      float f0 = fminf(fminf(dr[0], dr[1]), dr[2]);
      float f1 = fminf(fminf(dr[3], dr[4]), dr[5]);
      float f2 = fminf(fminf(dr[6], dr[7]), dr[8]);
      float f3 = fminf(fminf(dr[9], dr[10]), dr[11]);
      float f4 = fminf(fminf(dr[12], dr[13]), dr[14]);
      float g0 = fminf(fminf(f0, f1), dr[15]);
      float g1 = fminf(fminf(f2, f3), f4);
      mn[qt] = fminf(fminf(g0, g1), mn[qt]);
    }
    a = an;
  }

#pragma unroll
  for (int qt = 0; qt < QT; ++qt) {
    float m = fminf(mn[qt], __shfl_xor(mn[qt], 32));
    if (lane < 32) {
      unsigned bb = __float_as_uint(m);
      unsigned e = (bb & 0x80000000u) ? ~bb : (bb | 0x80000000u);
      atomicMin(&minarr[qbase + qt * 32 + lane], e);
    }
  }

  // ---- last block of this dir does the per-dir reduction ----
  // NO __threadfence (R8/R10/R11 post-mortem: device fences emit
  // buffer_wbl2/buffer_inv that serialized device-wide). Cross-block data
  // moves through device-scope atomics; __syncthreads' implicit
  // s_waitcnt vmcnt(0) drains our atomicMins before the ticket increment.
  __syncthreads();
  if (t == 0)
    s_ticket = __hip_atomic_fetch_add(&dcnt[d], 1u, __ATOMIC_RELAXED,
                                      __HIP_MEMORY_SCOPE_AGENT);
  __syncthreads();
  if (s_ticket != (unsigned)(BPD - 1)) return;

  float wsum = 0.0f, msum = 0.0f;
#pragma unroll 4
  for (int j = 0; j < 32; ++j) {
    int k = j * 256 + t;
    unsigned u = __hip_atomic_load(&minarr[(size_t)d * kNP + k],
                                   __ATOMIC_RELAXED, __HIP_MEMORY_SCOPE_AGENT);
    unsigned bb = (u & 0x80000000u) ? (u ^ 0x80000000u) : ~u;
    float mnv = __uint_as_float(bb);
    float4 P = pts[(size_t)d * kNP + k];
    if (P.w < 16384.0f) {
      wsum += P.w + mnv;
      msum += 1.0f;
    }
  }
#pragma unroll
  for (int off = 32; off; off >>= 1) {
    wsum += __shfl_down(wsum, off);
    msum += __shfl_down(msum, off);
  }
  if ((t & 63) == 0) { sw[t >> 6] = wsum; sm[t >> 6] = msum; }
  __syncthreads();
  if (t == 0) {
    float ws_ = sw[0] + sw[1] + sw[2] + sw[3];
    float ms_ = sm[0] + sm[1] + sm[2] + sm[3];
    __hip_atomic_store(&mval[d], ws_ / fmaxf(ms_, 1.0f), __ATOMIC_RELAXED,
                       __HIP_MEMORY_SCOPE_AGENT);
    // ACQ_REL: release publishes our mval store, acquire lets the final
    // winner read the other 15 mvals. Only 16 of these per launch.
    s_ticket = __hip_atomic_fetch_add(acnt, 1u, __ATOMIC_ACQ_REL,
                                      __HIP_MEMORY_SCOPE_AGENT);
  }
  __syncthreads();
  if (s_ticket != (unsigned)(kDirs - 1)) return;
  // ---- very last block combines 16 dir values into the 12 outputs ----
  if (t == 0) {
    float mv[kDirs];
    for (int dd = 0; dd < kDirs; ++dd)
      mv[dd] = __hip_atomic_load(&mval[dd], __ATOMIC_RELAXED,
                                 __HIP_MEMORY_SCOPE_AGENT);
    for (int s = 0; s < kS; ++s) {
      float acc = 0.0f;
      for (int b = 0; b < kB; ++b) {
        int p = b * kS + s;
        float tens = mv[2 * p] + mv[2 * p + 1];
        out[kS + s * kB + b] = tens;
        acc += tens;
      }
      out[s] = acc * (1.0f / kB);
    }
  }
}

extern "C" void kernel_launch(void* const* d_in, const int* in_sizes, int n_in,
                              void* d_out, int out_size, void* d_ws, size_t ws_size,
                              hipStream_t stream) {
  const float* rv = (const float*)d_in[0];
  const float* tgt = (const float*)d_in[1];
  float* ws = (float*)d_ws;
  float4* pts = (float4*)ws;
  unsigned* minarr = (unsigned*)(ws + OFF_MIN);
  float* mval = ws + OFF_MVAL;
  unsigned* dcnt = (unsigned*)(ws + OFF_DCNT);
  unsigned* acnt = (unsigned*)(ws + OFF_ACNT);
  float* out = (float*)d_out;

  hipLaunchKernelGGL(prep_kernel, dim3(kPairs * kNP / 256), dim3(256), 0, stream,
                     rv, tgt, pts, minarr, mval, dcnt, acnt);
  hipLaunchKernelGGL(nn_kernel, dim3(kDirs * NQB * NCC), dim3(256), 0, stream,
                     pts, minarr, mval, dcnt, acnt, out);
}